// Round 4
// baseline (86.914 us; speedup 1.0000x reference)
//
#include <hip/hip_runtime.h>

// Problem constants (pinned by the reference)
#define UNITS     49152
#define INPUT_DIM 15
#define BATCH     2048

constexpr int TPB            = 256;
constexpr int U_PER_THREAD   = 4;                     // float4 along U
constexpr int U_PER_BLOCK    = TPB * U_PER_THREAD;    // 1024
constexpr int ROWS_PER_BLOCK = 32;                    // batch rows per block

typedef float f32x4 __attribute__((ext_vector_type(4)));

// One-time (per launch) premask: mw[i][u] = w[i][u] * mask[u][i].
// Mask reads are per-thread contiguous (60 B), w reads/stores fully coalesced.
__global__ __launch_bounds__(TPB) void premask_kernel(
    const float* __restrict__ w,     // [INPUT_DIM, UNITS]
    const float* __restrict__ mask,  // [UNITS, INPUT_DIM]
    float* __restrict__ mw)          // [INPUT_DIM, UNITS]
{
    const int u = blockIdx.x * TPB + threadIdx.x;
    float m[INPUT_DIM];
#pragma unroll
    for (int i = 0; i < INPUT_DIM; ++i) m[i] = mask[(size_t)u * INPUT_DIM + i];
#pragma unroll
    for (int i = 0; i < INPUT_DIM; ++i)
        mw[(size_t)i * UNITS + u] = w[(size_t)i * UNITS + u] * m[i];
}

template <bool PREMASKED>
__global__ __launch_bounds__(TPB) void striatum_kernel(
    const float* __restrict__ x,     // [BATCH, INPUT_DIM]
    const float* __restrict__ w,     // [INPUT_DIM, UNITS] (premasked if PREMASKED)
    const float* __restrict__ bias,  // [UNITS]
    const float* __restrict__ mask,  // [UNITS, INPUT_DIM] (unused if PREMASKED)
    float* __restrict__ out)         // [BATCH, UNITS]
{
    __shared__ float xs[ROWS_PER_BLOCK * INPUT_DIM];  // 480 floats

    const int u0   = blockIdx.x * U_PER_BLOCK + threadIdx.x * U_PER_THREAD;
    const int row0 = blockIdx.y * ROWS_PER_BLOCK;

    // Cooperative load of the x row-tile into LDS
    for (int idx = threadIdx.x; idx < ROWS_PER_BLOCK * INPUT_DIM; idx += TPB) {
        xs[idx] = x[row0 * INPUT_DIM + idx];
    }

    // This thread's 4 weight columns in registers (coalesced float4 loads).
    f32x4 mw[INPUT_DIM];
#pragma unroll
    for (int i = 0; i < INPUT_DIM; ++i) {
        f32x4 wv = *reinterpret_cast<const f32x4*>(&w[(size_t)i * UNITS + u0]);
        if constexpr (!PREMASKED) {
            wv.x *= mask[(size_t)(u0 + 0) * INPUT_DIM + i];
            wv.y *= mask[(size_t)(u0 + 1) * INPUT_DIM + i];
            wv.z *= mask[(size_t)(u0 + 2) * INPUT_DIM + i];
            wv.w *= mask[(size_t)(u0 + 3) * INPUT_DIM + i];
        }
        mw[i] = wv;
    }
    const f32x4 bv = *reinterpret_cast<const f32x4*>(&bias[u0]);

    __syncthreads();

    // Stream ROWS_PER_BLOCK output rows; weights stay in registers.
    for (int r = 0; r < ROWS_PER_BLOCK; ++r) {
        const float* xr = &xs[r * INPUT_DIM];   // broadcast reads (same addr all lanes)
        f32x4 acc = bv;
#pragma unroll
        for (int i = 0; i < INPUT_DIM; ++i) {
            const float xv = xr[i];
            acc.x = fmaf(xv, mw[i].x, acc.x);
            acc.y = fmaf(xv, mw[i].y, acc.y);
            acc.z = fmaf(xv, mw[i].z, acc.z);
            acc.w = fmaf(xv, mw[i].w, acc.w);
        }
        // Plain (cached) streaming store — TCC write-combines full lines;
        // A/B vs nt-store: fillBuffer at 6.9 TB/s uses plain stores.
        *reinterpret_cast<f32x4*>(&out[(size_t)(row0 + r) * UNITS + u0]) = acc;
    }
}

extern "C" void kernel_launch(void* const* d_in, const int* in_sizes, int n_in,
                              void* d_out, int out_size, void* d_ws, size_t ws_size,
                              hipStream_t stream) {
    const float* x    = (const float*)d_in[0];  // inputs [2048, 15]
    const float* w    = (const float*)d_in[1];  // w      [15, 49152]
    const float* b    = (const float*)d_in[2];  // b      [49152]
    const float* mask = (const float*)d_in[3];  // mask   [49152, 15]
    float* out        = (float*)d_out;          // [2048, 49152]

    dim3 grid(UNITS / U_PER_BLOCK, BATCH / ROWS_PER_BLOCK);  // 48 x 64
    const size_t mw_bytes = (size_t)INPUT_DIM * UNITS * sizeof(float);  // 2.95 MB

    if (ws_size >= mw_bytes) {
        float* mw = (float*)d_ws;
        premask_kernel<<<UNITS / TPB, TPB, 0, stream>>>(w, mask, mw);
        striatum_kernel<true><<<grid, TPB, 0, stream>>>(x, mw, b, mask, out);
    } else {
        striatum_kernel<false><<<grid, TPB, 0, stream>>>(x, w, b, mask, out);
    }
}

// Round 5
// 83.932 us; speedup vs baseline: 1.0355x; 1.0355x over previous
//
#include <hip/hip_runtime.h>

// Problem constants (pinned by the reference)
#define UNITS     49152
#define INPUT_DIM 15
#define BATCH     2048

constexpr int TPB            = 256;
constexpr int U_PER_THREAD   = 4;                     // float4 along U
constexpr int U_PER_BLOCK    = TPB * U_PER_THREAD;    // 1024
constexpr int ROWS_PER_BLOCK = 64;                    // batch rows per block
constexpr int XS_STRIDE      = 16;                    // padded row stride (b128-friendly)

typedef float f32x4 __attribute__((ext_vector_type(4)));

// One-time premask: mw[i][u] = w[i][u] * mask[u][i] (coalesced; ~2 us)
__global__ __launch_bounds__(TPB) void premask_kernel(
    const float* __restrict__ w,     // [INPUT_DIM, UNITS]
    const float* __restrict__ mask,  // [UNITS, INPUT_DIM]
    float* __restrict__ mw)          // [INPUT_DIM, UNITS]
{
    const int u = blockIdx.x * TPB + threadIdx.x;
    float m[INPUT_DIM];
#pragma unroll
    for (int i = 0; i < INPUT_DIM; ++i) m[i] = mask[(size_t)u * INPUT_DIM + i];
#pragma unroll
    for (int i = 0; i < INPUT_DIM; ++i)
        mw[(size_t)i * UNITS + u] = w[(size_t)i * UNITS + u] * m[i];
}

template <bool PREMASKED>
__global__ __launch_bounds__(TPB, 4) void striatum_kernel(
    const float* __restrict__ x,     // [BATCH, INPUT_DIM]
    const float* __restrict__ w,     // [INPUT_DIM, UNITS] (premasked if PREMASKED)
    const float* __restrict__ bias,  // [UNITS]
    const float* __restrict__ mask,  // [UNITS, INPUT_DIM] (unused if PREMASKED)
    float* __restrict__ out)         // [BATCH, UNITS]
{
    // x tile, padded to 16 floats/row so each row is 4x ds_read_b128 (64B aligned)
    __shared__ __align__(16) float xs[ROWS_PER_BLOCK * XS_STRIDE];

    const int u0   = blockIdx.x * U_PER_BLOCK + threadIdx.x * U_PER_THREAD;
    const int row0 = blockIdx.y * ROWS_PER_BLOCK;

    // Cooperative load of the x row-tile into padded LDS (1024 slots, 4 iters)
    for (int idx = threadIdx.x; idx < ROWS_PER_BLOCK * XS_STRIDE; idx += TPB) {
        const int row = idx >> 4, col = idx & 15;
        xs[idx] = (col < INPUT_DIM) ? x[(size_t)(row0 + row) * INPUT_DIM + col] : 0.0f;
    }

    // This thread's 4 weight columns in registers (coalesced float4 loads).
    f32x4 mw[INPUT_DIM];
#pragma unroll
    for (int i = 0; i < INPUT_DIM; ++i) {
        f32x4 wv = *reinterpret_cast<const f32x4*>(&w[(size_t)i * UNITS + u0]);
        if constexpr (!PREMASKED) {
            wv.x *= mask[(size_t)(u0 + 0) * INPUT_DIM + i];
            wv.y *= mask[(size_t)(u0 + 1) * INPUT_DIM + i];
            wv.z *= mask[(size_t)(u0 + 2) * INPUT_DIM + i];
            wv.w *= mask[(size_t)(u0 + 3) * INPUT_DIM + i];
        }
        mw[i] = wv;
    }
    const f32x4 bv = *reinterpret_cast<const f32x4*>(&bias[u0]);

    __syncthreads();

    const f32x4* xs4 = reinterpret_cast<const f32x4*>(xs);

    // 2 rows per iteration: 8 independent ds_read_b128 + 2 stores in flight.
    for (int r = 0; r < ROWS_PER_BLOCK; r += 2) {
        f32x4 xa[4], xb[4];
#pragma unroll
        for (int j = 0; j < 4; ++j) {
            xa[j] = xs4[(r + 0) * 4 + j];
            xb[j] = xs4[(r + 1) * 4 + j];
        }
        // Constant-indexed flattening -> stays in registers
        const float va[16] = {xa[0].x, xa[0].y, xa[0].z, xa[0].w,
                              xa[1].x, xa[1].y, xa[1].z, xa[1].w,
                              xa[2].x, xa[2].y, xa[2].z, xa[2].w,
                              xa[3].x, xa[3].y, xa[3].z, xa[3].w};
        const float vb[16] = {xb[0].x, xb[0].y, xb[0].z, xb[0].w,
                              xb[1].x, xb[1].y, xb[1].z, xb[1].w,
                              xb[2].x, xb[2].y, xb[2].z, xb[2].w,
                              xb[3].x, xb[3].y, xb[3].z, xb[3].w};
        f32x4 acc0 = bv, acc1 = bv;
#pragma unroll
        for (int i = 0; i < INPUT_DIM; ++i) {
            acc0.x = fmaf(va[i], mw[i].x, acc0.x);
            acc0.y = fmaf(va[i], mw[i].y, acc0.y);
            acc0.z = fmaf(va[i], mw[i].z, acc0.z);
            acc0.w = fmaf(va[i], mw[i].w, acc0.w);
            acc1.x = fmaf(vb[i], mw[i].x, acc1.x);
            acc1.y = fmaf(vb[i], mw[i].y, acc1.y);
            acc1.z = fmaf(vb[i], mw[i].z, acc1.z);
            acc1.w = fmaf(vb[i], mw[i].w, acc1.w);
        }
        __builtin_nontemporal_store(acc0, reinterpret_cast<f32x4*>(&out[(size_t)(row0 + r + 0) * UNITS + u0]));
        __builtin_nontemporal_store(acc1, reinterpret_cast<f32x4*>(&out[(size_t)(row0 + r + 1) * UNITS + u0]));
    }
}

extern "C" void kernel_launch(void* const* d_in, const int* in_sizes, int n_in,
                              void* d_out, int out_size, void* d_ws, size_t ws_size,
                              hipStream_t stream) {
    const float* x    = (const float*)d_in[0];  // inputs [2048, 15]
    const float* w    = (const float*)d_in[1];  // w      [15, 49152]
    const float* b    = (const float*)d_in[2];  // b      [49152]
    const float* mask = (const float*)d_in[3];  // mask   [49152, 15]
    float* out        = (float*)d_out;          // [2048, 49152]

    dim3 grid(UNITS / U_PER_BLOCK, BATCH / ROWS_PER_BLOCK);  // 48 x 32
    const size_t mw_bytes = (size_t)INPUT_DIM * UNITS * sizeof(float);  // 2.95 MB

    if (ws_size >= mw_bytes) {
        float* mw = (float*)d_ws;
        premask_kernel<<<UNITS / TPB, TPB, 0, stream>>>(w, mask, mw);
        striatum_kernel<true><<<grid, TPB, 0, stream>>>(x, mw, b, mask, out);
    } else {
        striatum_kernel<false><<<grid, TPB, 0, stream>>>(x, w, b, mask, out);
    }
}